// Round 1
// baseline (275.569 us; speedup 1.0000x reference)
//
#include <hip/hip_runtime.h>
#include <hip/hip_bf16.h>

typedef __attribute__((ext_vector_type(4))) float f32x4;
typedef __attribute__((ext_vector_type(8))) short s16x8;

constexpr int NN   = 8192;
constexpr int KIN  = 512;
constexpr int KOUT = 128;

// round-to-nearest-even f32 -> bf16 bits
__device__ __forceinline__ ushort f2bf(float x) {
    union { float f; unsigned u; } v; v.f = x;
    unsigned r = (v.u + 0x7fffu + ((v.u >> 16) & 1u)) >> 16;
    return (ushort)r;
}

// ---------------- Kernel A: h = input @ W ; hT(bf16), s, t ----------------
__global__ __launch_bounds__(256) void kA(const float* __restrict__ inp,
                                          const float* __restrict__ W,
                                          const float* __restrict__ a_s,
                                          const float* __restrict__ a_n,
                                          ushort* __restrict__ hT,
                                          float* __restrict__ s_out,
                                          float* __restrict__ t_out) {
    __shared__ float smem[32 * 512];           // 64 KB input tile; reused as h_lds[32][128]
    const int t = threadIdx.x;
    const int rbase = blockIdx.x * 32;

    // stage 32x512 input tile
#pragma unroll
    for (int it = 0; it < 16; ++it) {
        int idx = it * 256 + t;                 // float4 units
        int r = idx >> 7;
        int c4 = (idx & 127) << 2;
        *(f32x4*)(&smem[r * 512 + c4]) =
            *(const f32x4*)(inp + (size_t)(rbase + r) * KIN + c4);
    }
    __syncthreads();

    // each thread: 4 rows x 4 cols
    const int c0 = (t & 31) * 4;
    const int rg = (t >> 5) * 4;
    float acc[4][4] = {};
#pragma unroll 4
    for (int k = 0; k < KIN; ++k) {
        f32x4 w4 = *(const f32x4*)(W + (size_t)k * KOUT + c0);
        float a0 = smem[(rg + 0) * 512 + k];
        float a1 = smem[(rg + 1) * 512 + k];
        float a2 = smem[(rg + 2) * 512 + k];
        float a3 = smem[(rg + 3) * 512 + k];
#pragma unroll
        for (int cc = 0; cc < 4; ++cc) {
            acc[0][cc] += a0 * w4[cc];
            acc[1][cc] += a1 * w4[cc];
            acc[2][cc] += a2 * w4[cc];
            acc[3][cc] += a3 * w4[cc];
        }
    }
    __syncthreads();

    float* h_lds = smem;                        // [32][128]
#pragma unroll
    for (int rr = 0; rr < 4; ++rr) {
        f32x4 v = {acc[rr][0], acc[rr][1], acc[rr][2], acc[rr][3]};
        *(f32x4*)(&h_lds[(rg + rr) * 128 + c0]) = v;
    }
    __syncthreads();

    // transposed bf16 write: thread -> (col = t>>1, 16 rows)
    {
        const int col = t >> 1;
        const int r0 = (t & 1) * 16;
        ushort tmp[16];
#pragma unroll
        for (int rr = 0; rr < 16; ++rr) tmp[rr] = f2bf(h_lds[(r0 + rr) * 128 + col]);
        ushort* dst = hT + (size_t)col * NN + rbase + r0;
        *(f32x4*)dst = *(f32x4*)&tmp[0];
        *(f32x4*)(dst + 8) = *(f32x4*)&tmp[8];
    }

    // s,t: per-wave row dots with shuffle reduce
    {
        const int w = t >> 6, lane = t & 63;
        float as1 = a_s[lane], as2 = a_s[64 + lane];
        float an1 = a_n[lane], an2 = a_n[64 + lane];
#pragma unroll
        for (int rr = 0; rr < 8; ++rr) {
            int row = w * 8 + rr;
            float h1 = h_lds[row * 128 + lane];
            float h2 = h_lds[row * 128 + 64 + lane];
            float ps = h1 * as1 + h2 * as2;
            float pt = h1 * an1 + h2 * an2;
#pragma unroll
            for (int off = 32; off; off >>= 1) {
                ps += __shfl_xor(ps, off);
                pt += __shfl_xor(pt, off);
            }
            if (lane == 0) {
                s_out[rbase + row] = ps;
                t_out[rbase + row] = pt;
            }
        }
    }
}

// ---------------- Kernel B: fused mask/lrelu/exp + PV via MFMA ----------------
// grid 512: bid = rb*4 + jc ; block 256 = 4 waves, wave w owns rows rb*64+w*16..+15
__global__ __launch_bounds__(256) void kB(const float* __restrict__ Mmat,
                                          const float* __restrict__ adjm,
                                          const ushort* __restrict__ hT,
                                          const float* __restrict__ s_in,
                                          const float* __restrict__ t_in,
                                          float* __restrict__ o_part,
                                          float* __restrict__ l_part) {
    const int bid = blockIdx.x;
    const int rb = bid >> 2;
    const int jc = bid & 3;
    const int tid = threadIdx.x;
    const int w = tid >> 6;
    const int lane = tid & 63;
    const int lrow = lane & 15;          // A-frag row
    const int kgrp = lane >> 4;          // A-frag k-group
    const int i = rb * 64 + w * 16 + lrow;
    const float si = s_in[i];
    const size_t Mbase = (size_t)i * NN;

    f32x4 acc[8];
#pragma unroll
    for (int ct = 0; ct < 8; ++ct) acc[ct] = (f32x4){0.f, 0.f, 0.f, 0.f};
    float lsum = 0.f;

    const int j0 = jc * 2048;
#pragma unroll 2
    for (int jb = j0; jb < j0 + 2048; jb += 32) {
        const int jj = jb + kgrp * 8;
        f32x4 m0 = *(const f32x4*)(Mmat + Mbase + jj);
        f32x4 m1 = *(const f32x4*)(Mmat + Mbase + jj + 4);
        f32x4 d0 = *(const f32x4*)(adjm + Mbase + jj);
        f32x4 d1 = *(const f32x4*)(adjm + Mbase + jj + 4);
        f32x4 t0 = *(const f32x4*)(t_in + jj);
        f32x4 t1 = *(const f32x4*)(t_in + jj + 4);

        float pv[8];
#pragma unroll
        for (int e = 0; e < 4; ++e) {
            float x = (si + t0[e]) * m0[e];
            x = x > 0.f ? x : 0.2f * x;
            pv[e] = d0[e] > 0.f ? __expf(x) : 0.f;
        }
#pragma unroll
        for (int e = 0; e < 4; ++e) {
            float x = (si + t1[e]) * m1[e];
            x = x > 0.f ? x : 0.2f * x;
            pv[4 + e] = d1[e] > 0.f ? __expf(x) : 0.f;
        }
        lsum += ((pv[0] + pv[1]) + (pv[2] + pv[3])) + ((pv[4] + pv[5]) + (pv[6] + pv[7]));

        s16x8 afrag;
#pragma unroll
        for (int e = 0; e < 8; ++e) afrag[e] = (short)f2bf(pv[e]);

#pragma unroll
        for (int ct = 0; ct < 8; ++ct) {
            const ushort* bp = hT + (size_t)(ct * 16 + lrow) * NN + jj;
            s16x8 bfrag = *(const s16x8*)bp;
            acc[ct] = __builtin_amdgcn_mfma_f32_16x16x32_bf16(afrag, bfrag, acc[ct], 0, 0, 0);
        }
    }

    // denominator: lanes {l, l^16, l^32, l^48} share a row
    lsum += __shfl_xor(lsum, 16);
    lsum += __shfl_xor(lsum, 32);
    if (lane < 16) l_part[(size_t)jc * NN + i] = lsum;

    // store o partials (D layout: row=(lane>>4)*4+reg, col=lane&15)
    float* op = o_part + (size_t)jc * NN * KOUT;
#pragma unroll
    for (int ct = 0; ct < 8; ++ct) {
#pragma unroll
        for (int r = 0; r < 4; ++r) {
            int gi = rb * 64 + w * 16 + kgrp * 4 + r;
            int col = ct * 16 + lrow;
            op[(size_t)gi * KOUT + col] = acc[ct][r];
        }
    }
}

// ---------------- Kernel C: reduce partials, divide, ELU ----------------
__global__ __launch_bounds__(256) void kC(const float* __restrict__ o_part,
                                          const float* __restrict__ l_part,
                                          float* __restrict__ out) {
    const int idx = blockIdx.x * 256 + threadIdx.x;   // 0 .. 1M-1
    const int i = idx >> 7;
    float osum = 0.f, lsum = 0.f;
#pragma unroll
    for (int p = 0; p < 4; ++p) {
        osum += o_part[(size_t)p * NN * KOUT + idx];
        lsum += l_part[(size_t)p * NN + i];
    }
    float v = osum / lsum;
    out[idx] = v > 0.f ? v : (__expf(v) - 1.f);
}

extern "C" void kernel_launch(void* const* d_in, const int* in_sizes, int n_in,
                              void* d_out, int out_size, void* d_ws, size_t ws_size,
                              hipStream_t stream) {
    const float* inp = (const float*)d_in[0];
    const float* adj = (const float*)d_in[1];
    const float* Mm  = (const float*)d_in[2];
    const float* W   = (const float*)d_in[3];
    const float* a_s = (const float*)d_in[4];
    const float* a_n = (const float*)d_in[5];
    float* out = (float*)d_out;

    char* ws = (char*)d_ws;
    ushort* hT    = (ushort*)(ws + 0);              //  2 MB  [128][8192] bf16
    float*  s_buf = (float*)(ws + 2097152);         // 32 KB
    float*  t_buf = (float*)(ws + 2129920);         // 32 KB
    float*  l_prt = (float*)(ws + 2162688);         // 128 KB [4][8192]
    float*  o_prt = (float*)(ws + 4194304);         // 16 MB  [4][8192][128]

    hipLaunchKernelGGL(kA, dim3(256), dim3(256), 0, stream, inp, W, a_s, a_n, hT, s_buf, t_buf);
    hipLaunchKernelGGL(kB, dim3(512), dim3(256), 0, stream, Mm, adj, hT, s_buf, t_buf, o_prt, l_prt);
    hipLaunchKernelGGL(kC, dim3(4096), dim3(256), 0, stream, o_prt, l_prt, out);
}